// Round 1
// baseline (43.404 us; speedup 1.0000x reference)
//
#include <hip/hip_runtime.h>

// YOLO v1 loss, fp32. preds/labels: [B, 7, 7, 30] fp32. Output: scalar fp32.
// One thread per (b,s,s) cell; deterministic 2-stage reduction.

#define LAMBDA_COORD 5.0f
#define LAMBDA_NOOBJ 0.5f

__device__ __forceinline__ float iou_xywh(const float* b1, const float* b2) {
    float b1x1 = b1[0] - b1[2] * 0.5f;
    float b1y1 = b1[1] - b1[3] * 0.5f;
    float b1x2 = b1[0] + b1[2] * 0.5f;
    float b1y2 = b1[1] + b1[3] * 0.5f;
    float b2x1 = b2[0] - b2[2] * 0.5f;
    float b2y1 = b2[1] - b2[3] * 0.5f;
    float b2x2 = b2[0] + b2[2] * 0.5f;
    float b2y2 = b2[1] + b2[3] * 0.5f;
    float iw = fmaxf(fminf(b1x2, b2x2) - fmaxf(b1x1, b2x1), 0.0f);
    float ih = fmaxf(fminf(b1y2, b2y2) - fmaxf(b1y1, b2y1), 0.0f);
    float inter = iw * ih;
    float area1 = (b1x2 - b1x1) * (b1y2 - b1y1);
    float area2 = (b2x2 - b2x1) * (b2y2 - b2y1);
    return inter / (area1 + area2 - inter + 1e-10f);
}

__device__ __forceinline__ float block_reduce_sum(float v, float* smem) {
    // wave64 shuffle reduce
    #pragma unroll
    for (int off = 32; off > 0; off >>= 1)
        v += __shfl_down(v, off, 64);
    int lane = threadIdx.x & 63;
    int wid  = threadIdx.x >> 6;
    if (lane == 0) smem[wid] = v;
    __syncthreads();
    float total = 0.0f;
    if (threadIdx.x == 0) {
        int nw = blockDim.x >> 6;
        for (int i = 0; i < nw; ++i) total += smem[i];
    }
    return total;  // valid only on thread 0
}

__global__ void __launch_bounds__(256) yolo_partial(
        const float* __restrict__ preds,
        const float* __restrict__ labels,
        float* __restrict__ partial,
        int ncells) {
    __shared__ float smem[4];
    float acc = 0.0f;
    int stride = gridDim.x * blockDim.x;
    for (int c = blockIdx.x * blockDim.x + threadIdx.x; c < ncells; c += stride) {
        // cell base = c*30 floats = c*120 bytes -> always 8B aligned: float2 loads
        const float2* p2 = reinterpret_cast<const float2*>(preds) + (size_t)c * 15;
        const float2* l2 = reinterpret_cast<const float2*>(labels) + (size_t)c * 15;
        float p[30], l[30];
        #pragma unroll
        for (int i = 0; i < 15; ++i) {
            float2 tp = p2[i];
            float2 tl = l2[i];
            p[2 * i]     = tp.x;
            p[2 * i + 1] = tp.y;
            l[2 * i]     = tl.x;
            l[2 * i + 1] = tl.y;
        }

        bool obj  = (l[4] == 1.0f);
        float iou1 = iou_xywh(p + 0, l + 0);
        float iou2 = iou_xywh(p + 5, l + 0);
        bool box1 = (iou1 > iou2);

        float dx1 = l[0] - p[0], dy1 = l[1] - p[1];
        float xy1 = dx1 * dx1 + dy1 * dy1;
        float dx2 = l[5] - p[5], dy2 = l[6] - p[6];
        float xy2 = dx2 * dx2 + dy2 * dy2;

        float dw1 = sqrtf(l[2]) - sqrtf(p[2]);
        float dh1 = sqrtf(l[3]) - sqrtf(p[3]);
        float wh1 = dw1 * dw1 + dh1 * dh1;
        float dw2 = sqrtf(l[7]) - sqrtf(p[7]);
        float dh2 = sqrtf(l[8]) - sqrtf(p[8]);
        float wh2 = dw2 * dw2 + dh2 * dh2;

        float dc1 = l[4] - p[4];
        float conf1 = dc1 * dc1;
        float dc2 = l[9] - p[9];
        float conf2 = dc2 * dc2;

        float cls = 0.0f;
        #pragma unroll
        for (int k = 10; k < 30; ++k) {
            float d = l[k] - p[k];
            cls = fmaf(d, d, cls);
        }

        float cell;
        if (obj) {
            float xy  = box1 ? xy1 : xy2;
            float wh  = box1 ? wh1 : wh2;
            float cf  = box1 ? conf1 : conf2;
            float no  = box1 ? p[9] * p[9] : p[4] * p[4];
            cell = LAMBDA_COORD * (xy + wh) + cf + LAMBDA_NOOBJ * no + cls;
        } else {
            cell = LAMBDA_NOOBJ * (p[4] * p[4] + p[9] * p[9]);
        }
        acc += cell;
    }

    float bsum = block_reduce_sum(acc, smem);
    if (threadIdx.x == 0) partial[blockIdx.x] = bsum;
}

__global__ void __launch_bounds__(256) yolo_finalize(
        const float* __restrict__ partial,
        int npartial,
        float* __restrict__ out,
        float inv_batch) {
    __shared__ float smem[4];
    float acc = 0.0f;
    for (int i = threadIdx.x; i < npartial; i += blockDim.x)
        acc += partial[i];
    float total = block_reduce_sum(acc, smem);
    if (threadIdx.x == 0) out[0] = total * inv_batch;
}

extern "C" void kernel_launch(void* const* d_in, const int* in_sizes, int n_in,
                              void* d_out, int out_size, void* d_ws, size_t ws_size,
                              hipStream_t stream) {
    const float* preds  = (const float*)d_in[0];
    const float* labels = (const float*)d_in[1];
    float* out = (float*)d_out;
    float* partial = (float*)d_ws;

    int ncells = in_sizes[0] / 30;           // B * 7 * 7
    int batch  = ncells / 49;                // B
    float inv_batch = 1.0f / (float)batch;

    const int block = 256;
    int grid = (ncells + block - 1) / block; // 3136 at B=16384
    int maxblocks = (int)(ws_size / sizeof(float));
    if (grid > maxblocks) grid = maxblocks;  // grid-stride covers the rest
    if (grid < 1) grid = 1;

    yolo_partial<<<grid, block, 0, stream>>>(preds, labels, partial, ncells);
    yolo_finalize<<<1, block, 0, stream>>>(partial, grid, out, inv_batch);
}